// Round 9
// baseline (541.735 us; speedup 1.0000x reference)
//
#include <hip/hip_runtime.h>
#include <stdint.h>

#define H 256
#define NATOMS 100000
#define MB 32
#define NBLK (NATOMS / MB)   // 3125

typedef float floatx4 __attribute__((ext_vector_type(4)));
typedef float floatx16 __attribute__((ext_vector_type(16)));
typedef short short8 __attribute__((ext_vector_type(8)));
typedef short short4v __attribute__((ext_vector_type(4)));

// lgkm-only barrier: global prefetches stay in flight across it.
#define BAR() do { asm volatile("s_waitcnt lgkmcnt(0)\n\ts_barrier" ::: "memory"); __builtin_amdgcn_sched_barrier(0); } while (0)

__device__ __forceinline__ unsigned short f2bf(float x) {
    union { float f; uint32_t u; } c; c.f = x;
    return (unsigned short)((c.u + 0x7FFFu + ((c.u >> 16) & 1u)) >> 16);
}
__device__ __forceinline__ float bf2f(unsigned short h) {
    union { uint32_t u; float f; } c; c.u = ((uint32_t)h) << 16; return c.f;
}
__device__ __forceinline__ uint32_t pk2(float lo, float hi) {
    return (uint32_t)f2bf(lo) | ((uint32_t)f2bf(hi) << 16);
}
__device__ __forceinline__ float upk(uint32_t u, int hi) {
    union { uint32_t u; float f; } c;
    c.u = hi ? (u & 0xFFFF0000u) : (u << 16);
    return c.f;
}

// ---------------------------------------------------------------------------
// Pack weights (f32 [K][N] row-major) into bf16 32x32x16 MFMA-B-frag order.
// frag fl = nb32*(K/16)+kf; lane l holds W[kf*16+(l>>5)*8+e][nb32*32+(l&31)].
// ws layout (bf16 elems): U@0, V@65536, W1@131072, W2@262144 (896KB total).
// ---------------------------------------------------------------------------
__global__ void pack_weights(const float* __restrict__ U_W, const float* __restrict__ V_W,
                             const float* __restrict__ W1, const float* __restrict__ W2,
                             unsigned short* __restrict__ P) {
    int gtid = blockIdx.x * 256 + threadIdx.x;
    int fid = gtid >> 6, l = gtid & 63;
    const float* src; int K, N, fl; unsigned short* dst;
    if (fid < 128)      { src = U_W; K = 256; N = 256; fl = fid;       dst = P; }
    else if (fid < 256) { src = V_W; K = 256; N = 256; fl = fid - 128; dst = P + 65536; }
    else if (fid < 512) { src = W1;  K = 512; N = 256; fl = fid - 256; dst = P + 131072; }
    else                { src = W2;  K = 256; N = 768; fl = fid - 512; dst = P + 262144; }
    int kbc = K >> 4;                    // frags per 32-col block
    int nb = fl / kbc, kf = fl - nb * kbc;
    int k0 = kf * 16 + ((l >> 5) << 3);
    int n0 = nb * 32 + (l & 31);
    short8 outv;
#pragma unroll
    for (int e = 0; e < 8; e++) outv[e] = (short)f2bf(src[(size_t)(k0 + e) * N + n0]);
    *(short8*)(dst + (size_t)fl * 512 + l * 8) = outv;
}

// ---------------------------------------------------------------------------
// Fused PaiNN mixing with 32x32x16 MFMA. Block = 32 atoms, 512 thr (8 waves),
// LDS 64KB -> 2 blocks/CU (two independent barrier domains). Wave w owns
// cols [32w,32w+32); lane col c = 32w + (l&31).
// LDS: 16-row frags, 1KB each, kpos-XOR swizzled (R8 layout, unchanged):
//   element (r15,koff32): kpos=(koff>>3)&3, byte=kpos*256+((r15^kpos)<<4)+(koff&7)*2
// A 32x32x16 operand (row=l&31, k=(l>>5)*8+e) reads these frags with
//   g=(l>>4)&1 frag select + parity kpos: off{E,O} lane constants.
// Map: [0,48K) VF v-frags (g*24+d*8+ks32); post-p1 overlays:
//   [0,16K) Vv_norm frags (g*8+ks32'), [16,32K) hid frags (g*8+ks32)
// [48K,64K) LNf s_norm frags (g*8+ks32) -> sdelta[a][c] (post-p3)
// Regs: raw s bf16 (srp), Uv packed bf16 (uvh 24), dotv/avv.
// ---------------------------------------------------------------------------
__global__ __launch_bounds__(512, 4) void painn_main(
    const float* __restrict__ s, const float* __restrict__ v,
    const float* __restrict__ gamma, const float* __restrict__ beta,
    const float* __restrict__ b1, const float* __restrict__ b2,
    const unsigned short* __restrict__ P,
    float* __restrict__ s_out, float* __restrict__ v_out) {

    __shared__ unsigned short SH[32768];   // 64KB
    char* LB = (char*)SH;

    const int tid = threadIdx.x;
    const int w = tid >> 6, l = tid & 63;
    const int l31 = l & 31, r15 = l & 15, hi5 = l >> 5;
    const int gA24 = ((l >> 4) & 1) * 24576;     // g-frag offset in VF
    const int gA8  = ((l >> 4) & 1) * 8192;      // g-frag offset in 16K slots
    const int kpE = hi5, kpO = 2 + hi5;
    const int offE = (kpE << 8) + ((r15 ^ kpE) << 4);
    const int offO = (kpO << 8) + ((r15 ^ kpO) << 4);
    const int atom0 = blockIdx.x * MB;
    const int aLN = tid >> 4, lg = tid & 15;     // LN map: 16 lanes/atom
    const int gLN = aLN >> 4, a15LN = aLN & 15;
    const int c = (w << 5) + l31;                // this lane's column
    const int kposC = l31 >> 3;                  // compute-map write kpos
    const int cb2 = (c & 7) << 1;

    // ---- stage v -> VF frags [0,48K) (R8 staging, unchanged) ----
    {
        const floatx4* vsrc = (const floatx4*)(v + (size_t)atom0 * 3 * H);
#pragma unroll
        for (int i = 0; i < 6; i++) {
            int p = i * 512 + tid;
            int a = p / 96, rem = p - a * 96;
            int d = rem >> 5, c8 = rem & 31;
            int q = ((a * 3 + d) << 6) + (c8 << 1);
            floatx4 x0 = vsrc[q], x1 = vsrc[q + 1];
            short8 pk;
#pragma unroll
            for (int j = 0; j < 4; j++) { pk[j] = (short)f2bf(x0[j]); pk[4 + j] = (short)f2bf(x1[j]); }
            int ks = c8 >> 2, kpos = c8 & 3;
            int bo = ((((a >> 4) * 24) + d * 8 + ks) << 10) + (kpos << 8) + (((a & 15) ^ kpos) << 4);
            *(short8*)(LB + bo) = pk;
        }
    }

    // ---- LayerNorm(s) -> LNf frags [48K,64K); raw s packed in regs ----
    short4v srp[4];
    {
        const floatx4* srow = (const floatx4*)(s + (size_t)(atom0 + aLN) * H);
        floatx4 vals[4];
        float sum = 0.f, sq = 0.f;
#pragma unroll
        for (int i = 0; i < 4; i++) {
            vals[i] = srow[lg + (i << 4)];
#pragma unroll
            for (int j = 0; j < 4; j++) { sum += vals[i][j]; sq += vals[i][j] * vals[i][j]; }
        }
#pragma unroll
        for (int m = 1; m < 16; m <<= 1) { sum += __shfl_xor(sum, m); sq += __shfl_xor(sq, m); }
        float mu = sum * (1.f / 256.f);
        float var = sq * (1.f / 256.f) - mu * mu;
        float rs = rsqrtf(var + 1e-5f);
#pragma unroll
        for (int i = 0; i < 4; i++) {
            int chunk = lg + (i << 4);
            floatx4 g4 = *(const floatx4*)(gamma + chunk * 4);
            floatx4 be4 = *(const floatx4*)(beta + chunk * 4);
            short4v pk, pr;
#pragma unroll
            for (int j = 0; j < 4; j++) {
                pk[j] = (short)f2bf((vals[i][j] - mu) * rs * g4[j] + be4[j]);
                pr[j] = (short)f2bf(vals[i][j]);
            }
            srp[i] = pr;
            int ks2 = chunk >> 3, kpos = (chunk >> 1) & 3, half = chunk & 1;
            int bo = 49152 + ((gLN * 8 + ks2) << 10) + (kpos << 8) + ((a15LN ^ kpos) << 4) + half * 8;
            *(short4v*)(LB + bo) = pk;
        }
    }

    // ---- p1 B prefetch before barrier ----
    const short8* PU = (const short8*)P;
    const short8* PV = (const short8*)(P + 65536);
    short8 bf[2];
    bf[0] = PU[(size_t)(w * 16) * 64 + l];

    BAR();  // B1: VF + LNf visible

    // ---- phase 1, U-pass: Uv (3 d-GEMMs M=32,N=32,K=256) ----
    floatx16 accA[3];
#pragma unroll
    for (int d = 0; d < 3; d++) accA[d] = (floatx16)0.f;
#pragma unroll
    for (int ks = 0; ks < 16; ks++) {
        int cur = ks & 1, nxt = cur ^ 1;
        if (ks < 15) bf[nxt] = PU[(size_t)(w * 16 + ks + 1) * 64 + l];
        int fb = ((ks >> 1) << 10) + ((ks & 1) ? offO : offE) + gA24;
        short8 af0 = *(const short8*)(LB + fb);
        short8 af1 = *(const short8*)(LB + fb + 8192);
        short8 af2 = *(const short8*)(LB + fb + 16384);
        __builtin_amdgcn_s_setprio(1);
        accA[0] = __builtin_amdgcn_mfma_f32_32x32x16_bf16(af0, bf[cur], accA[0], 0, 0, 0);
        accA[1] = __builtin_amdgcn_mfma_f32_32x32x16_bf16(af1, bf[cur], accA[1], 0, 0, 0);
        accA[2] = __builtin_amdgcn_mfma_f32_32x32x16_bf16(af2, bf[cur], accA[2], 0, 0, 0);
        __builtin_amdgcn_s_setprio(0);
    }
    // pack Uv -> bf16 pairs (24 VGPR), free accA for V
    uint32_t uvh[3][8];
#pragma unroll
    for (int d = 0; d < 3; d++)
#pragma unroll
        for (int p = 0; p < 8; p++) uvh[d][p] = pk2(accA[d][2 * p], accA[d][2 * p + 1]);

    // ---- phase 1, V-pass ----
    bf[0] = PV[(size_t)(w * 16) * 64 + l];
#pragma unroll
    for (int d = 0; d < 3; d++) accA[d] = (floatx16)0.f;
#pragma unroll
    for (int ks = 0; ks < 16; ks++) {
        int cur = ks & 1, nxt = cur ^ 1;
        if (ks < 15) bf[nxt] = PV[(size_t)(w * 16 + ks + 1) * 64 + l];
        int fb = ((ks >> 1) << 10) + ((ks & 1) ? offO : offE) + gA24;
        short8 af0 = *(const short8*)(LB + fb);
        short8 af1 = *(const short8*)(LB + fb + 8192);
        short8 af2 = *(const short8*)(LB + fb + 16384);
        __builtin_amdgcn_s_setprio(1);
        accA[0] = __builtin_amdgcn_mfma_f32_32x32x16_bf16(af0, bf[cur], accA[0], 0, 0, 0);
        accA[1] = __builtin_amdgcn_mfma_f32_32x32x16_bf16(af1, bf[cur], accA[1], 0, 0, 0);
        accA[2] = __builtin_amdgcn_mfma_f32_32x32x16_bf16(af2, bf[cur], accA[2], 0, 0, 0);
        __builtin_amdgcn_s_setprio(0);
    }

    // ---- fold: dot_uv (bf16 Uv x f32 Vv), ||Vv|| packed ----
    float dotv[16];
    uint32_t nvp[8];
#pragma unroll
    for (int p = 0; p < 8; p++) {
        float n0, n1;
        {
            int j = 2 * p;
            dotv[j] = upk(uvh[0][p], 0) * accA[0][j] + upk(uvh[1][p], 0) * accA[1][j]
                    + upk(uvh[2][p], 0) * accA[2][j];
            n0 = sqrtf(accA[0][j] * accA[0][j] + accA[1][j] * accA[1][j]
                     + accA[2][j] * accA[2][j] + 1e-8f);
        }
        {
            int j = 2 * p + 1;
            dotv[j] = upk(uvh[0][p], 1) * accA[0][j] + upk(uvh[1][p], 1) * accA[1][j]
                    + upk(uvh[2][p], 1) * accA[2][j];
            n1 = sqrtf(accA[0][j] * accA[0][j] + accA[1][j] * accA[1][j]
                     + accA[2][j] * accA[2][j] + 1e-8f);
        }
        nvp[p] = pk2(n0, n1);
    }

    // ---- p2 B prefetch (survives 2 barriers) ----
    const short8* PW1 = (const short8*)(P + 131072);
    bf[0] = PW1[(size_t)(w * 32) * 64 + l];

    BAR();  // B2: all VF reads done -> [0,16K) writable

    // ---- Vv_norm -> NMf frags [0,16K): frag g*8 + w (k' = c) ----
#pragma unroll
    for (int j = 0; j < 16; j++) {
        int a = (j & 3) + ((j >> 2) << 3) + (hi5 << 2);
        unsigned short hb = (unsigned short)((j & 1) ? (nvp[j >> 1] >> 16) : (nvp[j >> 1] & 0xFFFF));
        int bo = (((a >> 4) * 8 + w) << 10) + (kposC << 8) + (((a & 15) ^ kposC) << 4) + cb2;
        *(unsigned short*)(LB + bo) = hb;
    }

    BAR();  // B3: norm frags visible

    // ---- phase 2: hid = silu(ctx_in @ W1 + b1), M=32, K=512, 2 acc chains ----
    floatx16 acc2a = (floatx16)0.f, acc2b = (floatx16)0.f;
#pragma unroll
    for (int ks = 0; ks < 32; ks++) {
        int cur = ks & 1, nxt = cur ^ 1;
        if (ks < 31) bf[nxt] = PW1[(size_t)(w * 32 + ks + 1) * 64 + l];
        int fb = (ks < 16)
            ? 49152 + ((ks >> 1) << 10) + ((ks & 1) ? offO : offE) + gA8
            : (((ks - 16) >> 1) << 10) + ((ks & 1) ? offO : offE) + gA8;
        short8 af = *(const short8*)(LB + fb);
        __builtin_amdgcn_s_setprio(1);
        if (ks < 16) acc2a = __builtin_amdgcn_mfma_f32_32x32x16_bf16(af, bf[cur], acc2a, 0, 0, 0);
        else         acc2b = __builtin_amdgcn_mfma_f32_32x32x16_bf16(af, bf[cur], acc2b, 0, 0, 0);
        __builtin_amdgcn_s_setprio(0);
    }
    // hid fold -> hid frags [16,32K) (disjoint from p2 read regions: no barrier)
    {
        float bb = b1[c];
#pragma unroll
        for (int j = 0; j < 16; j++) {
            int a = (j & 3) + ((j >> 2) << 3) + (hi5 << 2);
            float x = acc2a[j] + acc2b[j] + bb;
            float hh = x / (1.f + __expf(-x));
            int bo = 16384 + (((a >> 4) * 8 + w) << 10) + (kposC << 8) + (((a & 15) ^ kposC) << 4) + cb2;
            *(unsigned short*)(LB + bo) = f2bf(hh);
        }
    }

    // ---- p3 B prefetch (sv segment first) ----
    const short8* PW2 = (const short8*)(P + 262144);
    bf[0] = PW2[(size_t)((8 + w) * 16) * 64 + l];

    BAR();  // B4: hid visible (and all waves past p2 -> LNf reusable)

    // ---- phase 3: per-segment passes over hid (K=256), 2 acc chains each ----
    float svd[16];
    {   // sv (seg 1)
        floatx16 a3a = (floatx16)0.f, a3b = (floatx16)0.f;
#pragma unroll
        for (int ks = 0; ks < 16; ks++) {
            int cur = ks & 1, nxt = cur ^ 1;
            if (ks < 15) bf[nxt] = PW2[(size_t)((8 + w) * 16 + ks + 1) * 64 + l];
            int fb = 16384 + ((ks >> 1) << 10) + ((ks & 1) ? offO : offE) + gA8;
            short8 af = *(const short8*)(LB + fb);
            __builtin_amdgcn_s_setprio(1);
            if (ks < 8) a3a = __builtin_amdgcn_mfma_f32_32x32x16_bf16(af, bf[cur], a3a, 0, 0, 0);
            else        a3b = __builtin_amdgcn_mfma_f32_32x32x16_bf16(af, bf[cur], a3b, 0, 0, 0);
            __builtin_amdgcn_s_setprio(0);
        }
        float bsv = b2[256 + c];
#pragma unroll
        for (int j = 0; j < 16; j++) svd[j] = (a3a[j] + a3b[j] + bsv) * dotv[j];
    }
    {   // ss (seg 0) -> sdelta into LNf region [48K,64K)
        bf[0] = PW2[(size_t)(w * 16) * 64 + l];
        floatx16 a3a = (floatx16)0.f, a3b = (floatx16)0.f;
#pragma unroll
        for (int ks = 0; ks < 16; ks++) {
            int cur = ks & 1, nxt = cur ^ 1;
            if (ks < 15) bf[nxt] = PW2[(size_t)(w * 16 + ks + 1) * 64 + l];
            int fb = 16384 + ((ks >> 1) << 10) + ((ks & 1) ? offO : offE) + gA8;
            short8 af = *(const short8*)(LB + fb);
            __builtin_amdgcn_s_setprio(1);
            if (ks < 8) a3a = __builtin_amdgcn_mfma_f32_32x32x16_bf16(af, bf[cur], a3a, 0, 0, 0);
            else        a3b = __builtin_amdgcn_mfma_f32_32x32x16_bf16(af, bf[cur], a3b, 0, 0, 0);
            __builtin_amdgcn_s_setprio(0);
        }
        float bss = b2[c];
#pragma unroll
        for (int j = 0; j < 16; j++) {
            int a = (j & 3) + ((j >> 2) << 3) + (hi5 << 2);
            float sd = a3a[j] + a3b[j] + bss + svd[j];
            int bo = 49152 + (((a << 9) + (c << 1)) ^ ((a & 7) << 4));
            *(unsigned short*)(LB + bo) = f2bf(sd);
        }
    }
    {   // vv (seg 2) -> a_vv in regs (reuse svd)
        bf[0] = PW2[(size_t)((16 + w) * 16) * 64 + l];
        floatx16 a3a = (floatx16)0.f, a3b = (floatx16)0.f;
#pragma unroll
        for (int ks = 0; ks < 16; ks++) {
            int cur = ks & 1, nxt = cur ^ 1;
            if (ks < 15) bf[nxt] = PW2[(size_t)((16 + w) * 16 + ks + 1) * 64 + l];
            int fb = 16384 + ((ks >> 1) << 10) + ((ks & 1) ? offO : offE) + gA8;
            short8 af = *(const short8*)(LB + fb);
            __builtin_amdgcn_s_setprio(1);
            if (ks < 8) a3a = __builtin_amdgcn_mfma_f32_32x32x16_bf16(af, bf[cur], a3a, 0, 0, 0);
            else        a3b = __builtin_amdgcn_mfma_f32_32x32x16_bf16(af, bf[cur], a3b, 0, 0, 0);
            __builtin_amdgcn_s_setprio(0);
        }
        float bvv = b2[512 + c];
#pragma unroll
        for (int j = 0; j < 16; j++) svd[j] = a3a[j] + a3b[j] + bvv;
    }

    BAR();  // B5: sdelta visible

    // ---- epilogue: s_out (LN map; raw s from regs; coalesced) ----
    {
        size_t gb = (size_t)(atom0 + aLN) * H;
        int xo = (aLN & 7) << 4;
#pragma unroll
        for (int i = 0; i < 4; i++) {
            int chunk = lg + (i << 4);
            short4v sd4 = *(const short4v*)(LB + 49152 + ((((aLN << 9) + (chunk << 3))) ^ xo));
            floatx4 o;
#pragma unroll
            for (int j = 0; j < 4; j++) o[j] = bf2f((unsigned short)srp[i][j]) + bf2f((unsigned short)sd4[j]);
            *(floatx4*)(s_out + gb + chunk * 4) = o;
        }
    }

    // ---- epilogue: v_out = v + a_vv * Uv (compute map; v re-read, L2-warm) ----
#pragma unroll
    for (int j = 0; j < 16; j++) {
        int a = (j & 3) + ((j >> 2) << 3) + (hi5 << 2);
        size_t base = (size_t)(atom0 + a) * 3 * H + c;
        float av = svd[j];
#pragma unroll
        for (int d = 0; d < 3; d++) {
            float uv = upk(uvh[d][j >> 1], j & 1);
            size_t vi = base + (size_t)d * H;
            v_out[vi] = v[vi] + av * uv;
        }
    }
}

extern "C" void kernel_launch(void* const* d_in, const int* in_sizes, int n_in,
                              void* d_out, int out_size, void* d_ws, size_t ws_size,
                              hipStream_t stream) {
    const float* s     = (const float*)d_in[0];
    const float* v     = (const float*)d_in[1];
    const float* gamma = (const float*)d_in[2];
    const float* beta  = (const float*)d_in[3];
    const float* U_W   = (const float*)d_in[4];
    const float* V_W   = (const float*)d_in[5];
    const float* W1    = (const float*)d_in[6];
    const float* b1    = (const float*)d_in[7];
    const float* W2    = (const float*)d_in[8];
    const float* b2    = (const float*)d_in[9];
    float* s_out = (float*)d_out;
    float* v_out = s_out + (size_t)NATOMS * H;
    unsigned short* P = (unsigned short*)d_ws;   // needs 917504 B

    pack_weights<<<dim3(224), dim3(256), 0, stream>>>(U_W, V_W, W1, W2, P);
    painn_main<<<dim3(NBLK), dim3(512), 0, stream>>>(s, v, gamma, beta, b1, b2, P, s_out, v_out);
}

// Round 10
// 454.508 us; speedup vs baseline: 1.1919x; 1.1919x over previous
//
#include <hip/hip_runtime.h>
#include <stdint.h>

#define H 256
#define NATOMS 100000
#define MB 32
#define NBLK (NATOMS / MB)   // 3125

typedef float floatx4 __attribute__((ext_vector_type(4)));
typedef short short8 __attribute__((ext_vector_type(8)));
typedef short short4v __attribute__((ext_vector_type(4)));

// lgkm-only barrier: global prefetches stay in flight across it.
#define BAR() do { asm volatile("s_waitcnt lgkmcnt(0)\n\ts_barrier" ::: "memory"); __builtin_amdgcn_sched_barrier(0); } while (0)

__device__ __forceinline__ unsigned short f2bf(float x) {
    union { float f; uint32_t u; } c; c.f = x;
    return (unsigned short)((c.u + 0x7FFFu + ((c.u >> 16) & 1u)) >> 16);
}
__device__ __forceinline__ float bf2f(unsigned short h) {
    union { uint32_t u; float f; } c; c.u = ((uint32_t)h) << 16; return c.f;
}
__device__ __forceinline__ uint32_t pk2(float lo, float hi) {
    return (uint32_t)f2bf(lo) | ((uint32_t)f2bf(hi) << 16);
}
__device__ __forceinline__ float upk(uint32_t u, int hi) {
    union { uint32_t u; float f; } c;
    c.u = hi ? (u & 0xFFFF0000u) : (u << 16);
    return c.f;
}

// ---------------------------------------------------------------------------
// Pack weights (f32 [K][N] row-major) into bf16 MFMA-B-fragment order.
// frag fl = nb*(K/32)+kb; lane l holds W[kb*32+(l>>4)*8+e][nb*16+(l&15)].
// ws layout (bf16 elems): U@0, V@65536, W1@131072, W2@262144 (896KB total).
// ---------------------------------------------------------------------------
__global__ void pack_weights(const float* __restrict__ U_W, const float* __restrict__ V_W,
                             const float* __restrict__ W1, const float* __restrict__ W2,
                             unsigned short* __restrict__ P) {
    int gtid = blockIdx.x * 256 + threadIdx.x;
    int fid = gtid >> 6, l = gtid & 63;
    const float* src; int K, N, fl; unsigned short* dst;
    if (fid < 128)      { src = U_W; K = 256; N = 256; fl = fid;       dst = P; }
    else if (fid < 256) { src = V_W; K = 256; N = 256; fl = fid - 128; dst = P + 65536; }
    else if (fid < 512) { src = W1;  K = 512; N = 256; fl = fid - 256; dst = P + 131072; }
    else                { src = W2;  K = 256; N = 768; fl = fid - 512; dst = P + 262144; }
    int kbc = K >> 5;
    int nb = fl / kbc, kb = fl - nb * kbc;
    int k0 = kb * 32 + ((l >> 4) << 3);
    int n0 = nb * 16 + (l & 15);
    short8 outv;
#pragma unroll
    for (int e = 0; e < 8; e++) outv[e] = (short)f2bf(src[(size_t)(k0 + e) * N + n0]);
    *(short8*)(dst + (size_t)fl * 512 + l * 8) = outv;
}

// ---------------------------------------------------------------------------
// Fused PaiNN mixing (R8 structure + LDS-sourced raw v + nt stores).
// Block = 32 atoms, 512 thr (8 waves), LDS 64KB -> 2 blocks/CU (two
// independent barrier domains). Wave w owns cols [32w,32w+32) (cf 0..1).
// A-frags 1KB MFMA-linear w/ kpos-XOR swizzle;
// lane read off loff = (l>>4)*256 + ((l15^(l>>4))<<4).
// LDS map (one 64KB array):
//   [0,48K)  v-frags (g*24+d*8+ks)   [staging -> B2; raw-v LDS reads pre-B2]
//   [0,16K)  slotX: Vv_norm frags (g*8+kn)  [B2 -> p2], then sdelta[a][c]
//   [16K,32K) slotY: hid frags (g*8+ks)     [p2 -> p3]
//   [48K,64K) LNf: s_norm frags (g*8+ks)    [stage -> p2]
// In regs: raw s (bf16 srp), raw v (bf16 vrw), Uv (bf16 uvh), dotv, a_vv.
// Outputs via nontemporal stores; v/s staged via nontemporal loads.
// ---------------------------------------------------------------------------
__global__ __launch_bounds__(512, 4) void painn_main(
    const float* __restrict__ s, const float* __restrict__ v,
    const float* __restrict__ gamma, const float* __restrict__ beta,
    const float* __restrict__ b1, const float* __restrict__ b2,
    const unsigned short* __restrict__ P,
    float* __restrict__ s_out, float* __restrict__ v_out) {

    __shared__ unsigned short SH[32768];   // 64KB
    char* LB = (char*)SH;

    const int tid = threadIdx.x;
    const int w = tid >> 6, l = tid & 63;
    const int l15 = l & 15, lhi = l >> 4;
    const int loff = (lhi << 8) | ((l15 ^ lhi) << 4);
    const int atom0 = blockIdx.x * MB;
    const int aLN = tid >> 4, lg = tid & 15;          // 16 lanes per atom
    const int gLN = aLN >> 4, a15LN = aLN & 15;

    // ---- stage v -> v-frags [0,48K) (nontemporal loads) ----
    {
        const floatx4* vsrc = (const floatx4*)(v + (size_t)atom0 * 3 * H);
#pragma unroll
        for (int i = 0; i < 6; i++) {
            int p = i * 512 + tid;
            int a = p / 96, rem = p - a * 96;
            int d = rem >> 5, c8 = rem & 31;
            int q = ((a * 3 + d) << 6) + (c8 << 1);
            floatx4 x0 = __builtin_nontemporal_load(vsrc + q);
            floatx4 x1 = __builtin_nontemporal_load(vsrc + q + 1);
            short8 pk;
#pragma unroll
            for (int j = 0; j < 4; j++) { pk[j] = (short)f2bf(x0[j]); pk[4 + j] = (short)f2bf(x1[j]); }
            int ks = c8 >> 2, kpos = c8 & 3;
            int bo = ((((a >> 4) * 24) + d * 8 + ks) << 10) + (kpos << 8) + (((a & 15) ^ kpos) << 4);
            *(short8*)(LB + bo) = pk;
        }
    }

    // ---- LayerNorm(s) -> LNf frags [48K,64K); raw s packed in regs ----
    short4v srp[4];
    {
        const floatx4* srow = (const floatx4*)(s + (size_t)(atom0 + aLN) * H);
        floatx4 vals[4];
        float sum = 0.f, sq = 0.f;
#pragma unroll
        for (int i = 0; i < 4; i++) {
            vals[i] = __builtin_nontemporal_load(srow + lg + (i << 4));
#pragma unroll
            for (int j = 0; j < 4; j++) { sum += vals[i][j]; sq += vals[i][j] * vals[i][j]; }
        }
#pragma unroll
        for (int m = 1; m < 16; m <<= 1) { sum += __shfl_xor(sum, m); sq += __shfl_xor(sq, m); }
        float mu = sum * (1.f / 256.f);
        float var = sq * (1.f / 256.f) - mu * mu;
        float rs = rsqrtf(var + 1e-5f);
#pragma unroll
        for (int i = 0; i < 4; i++) {
            int chunk = lg + (i << 4);
            floatx4 g4 = *(const floatx4*)(gamma + chunk * 4);
            floatx4 be4 = *(const floatx4*)(beta + chunk * 4);
            short4v pk, pr;
#pragma unroll
            for (int j = 0; j < 4; j++) {
                pk[j] = (short)f2bf((vals[i][j] - mu) * rs * g4[j] + be4[j]);
                pr[j] = (short)f2bf(vals[i][j]);
            }
            srp[i] = pr;
            int ks2 = chunk >> 3, kpos = (chunk >> 1) & 3, half = chunk & 1;
            int bo = 49152 + ((gLN * 8 + ks2) << 10) + (kpos << 8) + ((a15LN ^ kpos) << 4) + half * 8;
            *(short4v*)(LB + bo) = pk;
        }
    }

    // ---- p1 B prefetch (cf=0, slot0) before barrier ----
    const short8* PU = (const short8*)P;
    const short8* PV = (const short8*)(P + 65536);
    short8 bU[2], bV[2];
    bU[0] = PU[(size_t)((w * 2) * 8) * 64 + l];
    bV[0] = PV[(size_t)((w * 2) * 8) * 64 + l];

    BAR();  // B1: v-frags + LNf visible

    // ---- phase 1: Uv & Vv, per-cf passes (keeps VGPR low) ----
    float dotv[2][2][4];
    uint32_t uvh[2][3][2][2];   // [cf][d][g][pair] packed bf16
    uint32_t nvp[2][2][2];      // [cf][g][pair]   packed bf16
#pragma unroll
    for (int cf = 0; cf < 2; cf++) {
        int nb = w * 2 + cf;
        floatx4 accU[3][2], accV[3][2];
#pragma unroll
        for (int d = 0; d < 3; d++)
#pragma unroll
            for (int g = 0; g < 2; g++) { accU[d][g] = (floatx4)0.f; accV[d][g] = (floatx4)0.f; }
#pragma unroll
        for (int ks = 0; ks < 8; ks++) {
            int cur = ks & 1, nxt = cur ^ 1;
            if (ks < 7) {
                bU[nxt] = PU[(size_t)(nb * 8 + ks + 1) * 64 + l];
                bV[nxt] = PV[(size_t)(nb * 8 + ks + 1) * 64 + l];
            } else if (cf == 0) {
                // chain next pass's slot0: no pass-boundary bubble
                bU[nxt] = PU[(size_t)((nb + 1) * 8) * 64 + l];
                bV[nxt] = PV[(size_t)((nb + 1) * 8) * 64 + l];
            }
#pragma unroll
            for (int g = 0; g < 2; g++) {
                short8 af0 = *(const short8*)(LB + ((g * 24 + 0 * 8 + ks) << 10) + loff);
                short8 af1 = *(const short8*)(LB + ((g * 24 + 1 * 8 + ks) << 10) + loff);
                short8 af2 = *(const short8*)(LB + ((g * 24 + 2 * 8 + ks) << 10) + loff);
                __builtin_amdgcn_s_setprio(1);
                accU[0][g] = __builtin_amdgcn_mfma_f32_16x16x32_bf16(af0, bU[cur], accU[0][g], 0, 0, 0);
                accV[0][g] = __builtin_amdgcn_mfma_f32_16x16x32_bf16(af0, bV[cur], accV[0][g], 0, 0, 0);
                accU[1][g] = __builtin_amdgcn_mfma_f32_16x16x32_bf16(af1, bU[cur], accU[1][g], 0, 0, 0);
                accV[1][g] = __builtin_amdgcn_mfma_f32_16x16x32_bf16(af1, bV[cur], accV[1][g], 0, 0, 0);
                accU[2][g] = __builtin_amdgcn_mfma_f32_16x16x32_bf16(af2, bU[cur], accU[2][g], 0, 0, 0);
                accV[2][g] = __builtin_amdgcn_mfma_f32_16x16x32_bf16(af2, bV[cur], accV[2][g], 0, 0, 0);
                __builtin_amdgcn_s_setprio(0);
            }
        }
        // fold: dot_uv, ||Vv||, pack Uv -> bf16
#pragma unroll
        for (int g = 0; g < 2; g++) {
            float nv[4];
#pragma unroll
            for (int j = 0; j < 4; j++) {
                dotv[cf][g][j] = accU[0][g][j] * accV[0][g][j] + accU[1][g][j] * accV[1][g][j]
                               + accU[2][g][j] * accV[2][g][j];
                nv[j] = sqrtf(accV[0][g][j] * accV[0][g][j] + accV[1][g][j] * accV[1][g][j]
                            + accV[2][g][j] * accV[2][g][j] + 1e-8f);
            }
            nvp[cf][g][0] = pk2(nv[0], nv[1]);
            nvp[cf][g][1] = pk2(nv[2], nv[3]);
#pragma unroll
            for (int d = 0; d < 3; d++) {
                uvh[cf][d][g][0] = pk2(accU[d][g][0], accU[d][g][1]);
                uvh[cf][d][g][1] = pk2(accU[d][g][2], accU[d][g][3]);
            }
        }
    }

    // ---- raw v for epilogue: read from VF frags BEFORE B2 overwrites them ----
    // element (a15, koff=c&31) of frag g*24+d*8+w; c = 32w+16cf+l15.
    uint32_t vrw[2][3][2][2];   // [cf][d][g][pair] packed bf16
#pragma unroll
    for (int cf = 0; cf < 2; cf++) {
        int kp = (cf << 1) | (l15 >> 3);
        int cbyte = (l15 & 7) << 1;
#pragma unroll
        for (int d = 0; d < 3; d++)
#pragma unroll
            for (int g = 0; g < 2; g++) {
                int fb = ((g * 24 + d * 8 + w) << 10) + (kp << 8) + cbyte;
                int a0 = (lhi << 2);
                unsigned short e0 = *(const unsigned short*)(LB + fb + (((a0 + 0) ^ kp) << 4));
                unsigned short e1 = *(const unsigned short*)(LB + fb + (((a0 + 1) ^ kp) << 4));
                unsigned short e2 = *(const unsigned short*)(LB + fb + (((a0 + 2) ^ kp) << 4));
                unsigned short e3 = *(const unsigned short*)(LB + fb + (((a0 + 3) ^ kp) << 4));
                vrw[cf][d][g][0] = (uint32_t)e0 | ((uint32_t)e1 << 16);
                vrw[cf][d][g][1] = (uint32_t)e2 | ((uint32_t)e3 << 16);
            }
    }

    BAR();  // B2: all v-frag reads done -> slotX/slotY writable

    // ---- Vv_norm -> slotX frags ----
#pragma unroll
    for (int cf = 0; cf < 2; cf++) {
        int kp = (cf << 1) | (l15 >> 3);
        int cb = (l15 & 7) << 1;
#pragma unroll
        for (int g = 0; g < 2; g++)
#pragma unroll
            for (int j = 0; j < 4; j++) {
                int a15 = (lhi << 2) + j;
                unsigned short hbits = (unsigned short)((j & 1) ? (nvp[cf][g][j >> 1] >> 16)
                                                                : (nvp[cf][g][j >> 1] & 0xFFFF));
                int bo = ((g * 8 + w) << 10) + (kp << 8) + ((a15 ^ kp) << 4) + cb;
                *(unsigned short*)(LB + bo) = hbits;
            }
    }

    // ---- p2 B prefetch ----
    const short8* PW1 = (const short8*)(P + 131072);
    short8 bw[2];
    bw[0] = PW1[(size_t)((w * 2) * 16) * 64 + l];

    BAR();  // B3: norm frags visible

    // ---- phase 2: hid = silu(ctx_in @ W1 + b1), per-cf passes ----
#pragma unroll
    for (int cf = 0; cf < 2; cf++) {
        int nb = w * 2 + cf;
        floatx4 acc2[2];
        acc2[0] = (floatx4)0.f; acc2[1] = (floatx4)0.f;
#pragma unroll
        for (int ks2 = 0; ks2 < 16; ks2++) {
            int cur = ks2 & 1, nxt = cur ^ 1;
            if (ks2 < 15) bw[nxt] = PW1[(size_t)(nb * 16 + ks2 + 1) * 64 + l];
            else if (cf == 0) bw[nxt] = PW1[(size_t)((nb + 1) * 16) * 64 + l];
            short8 af0 = (ks2 < 8)
                ? *(const short8*)(LB + 49152 + ((0 * 8 + ks2) << 10) + loff)
                : *(const short8*)(LB + ((0 * 8 + ks2 - 8) << 10) + loff);
            short8 af1 = (ks2 < 8)
                ? *(const short8*)(LB + 49152 + ((1 * 8 + ks2) << 10) + loff)
                : *(const short8*)(LB + ((1 * 8 + ks2 - 8) << 10) + loff);
            __builtin_amdgcn_s_setprio(1);
            acc2[0] = __builtin_amdgcn_mfma_f32_16x16x32_bf16(af0, bw[cur], acc2[0], 0, 0, 0);
            acc2[1] = __builtin_amdgcn_mfma_f32_16x16x32_bf16(af1, bw[cur], acc2[1], 0, 0, 0);
            __builtin_amdgcn_s_setprio(0);
        }
        // hid -> slotY frags (slotY free since B2; readers gated by B4)
        int c = (w << 5) + (cf << 4) + l15;
        float bb = b1[c];
        int kp = (cf << 1) | (l15 >> 3);
        int cb = (l15 & 7) << 1;
#pragma unroll
        for (int g = 0; g < 2; g++)
#pragma unroll
            for (int j = 0; j < 4; j++) {
                int a15 = (lhi << 2) + j;
                float x = acc2[g][j] + bb;
                float hh = x / (1.f + __expf(-x));
                int bo = 16384 + ((g * 8 + w) << 10) + (kp << 8) + ((a15 ^ kp) << 4) + cb;
                *(unsigned short*)(LB + bo) = f2bf(hh);
            }
    }

    // ---- p3 B prefetch (first pass = sv segment, sg=1) ----
    const short8* PW2 = (const short8*)(P + 262144);
    short8 b2w[2][2];
    b2w[0][0] = PW2[(size_t)((16 + w * 2 + 0) * 8) * 64 + l];
    b2w[0][1] = PW2[(size_t)((16 + w * 2 + 1) * 8) * 64 + l];

    BAR();  // B4: hid visible

    // ---- phase 3: per-segment passes sv -> ss -> vv ----
    float svd[2][2][4];   // sv*dot -> sdelta -> a_vv (reused)
    {   // sv (sg=1)
        floatx4 acc[2][2];
#pragma unroll
        for (int g = 0; g < 2; g++) { acc[g][0] = (floatx4)0.f; acc[g][1] = (floatx4)0.f; }
#pragma unroll
        for (int ks3 = 0; ks3 < 8; ks3++) {
            int cur = ks3 & 1, nxt = cur ^ 1;
            if (ks3 < 7) {
                b2w[nxt][0] = PW2[(size_t)((16 + w * 2 + 0) * 8 + ks3 + 1) * 64 + l];
                b2w[nxt][1] = PW2[(size_t)((16 + w * 2 + 1) * 8 + ks3 + 1) * 64 + l];
            } else {
                b2w[nxt][0] = PW2[(size_t)((0 + w * 2 + 0) * 8) * 64 + l];
                b2w[nxt][1] = PW2[(size_t)((0 + w * 2 + 1) * 8) * 64 + l];
            }
            short8 af0 = *(const short8*)(LB + 16384 + ((0 * 8 + ks3) << 10) + loff);
            short8 af1 = *(const short8*)(LB + 16384 + ((1 * 8 + ks3) << 10) + loff);
            __builtin_amdgcn_s_setprio(1);
            acc[0][0] = __builtin_amdgcn_mfma_f32_16x16x32_bf16(af0, b2w[cur][0], acc[0][0], 0, 0, 0);
            acc[0][1] = __builtin_amdgcn_mfma_f32_16x16x32_bf16(af0, b2w[cur][1], acc[0][1], 0, 0, 0);
            acc[1][0] = __builtin_amdgcn_mfma_f32_16x16x32_bf16(af1, b2w[cur][0], acc[1][0], 0, 0, 0);
            acc[1][1] = __builtin_amdgcn_mfma_f32_16x16x32_bf16(af1, b2w[cur][1], acc[1][1], 0, 0, 0);
            __builtin_amdgcn_s_setprio(0);
        }
#pragma unroll
        for (int cf = 0; cf < 2; cf++) {
            float bsv = b2[256 + (w << 5) + (cf << 4) + l15];
#pragma unroll
            for (int g = 0; g < 2; g++)
#pragma unroll
                for (int j = 0; j < 4; j++)
                    svd[cf][g][j] = (acc[g][cf][j] + bsv) * dotv[cf][g][j];
        }
    }
    {   // ss (sg=0)
        floatx4 acc[2][2];
#pragma unroll
        for (int g = 0; g < 2; g++) { acc[g][0] = (floatx4)0.f; acc[g][1] = (floatx4)0.f; }
#pragma unroll
        for (int ks3 = 0; ks3 < 8; ks3++) {
            int cur = ks3 & 1, nxt = cur ^ 1;
            if (ks3 < 7) {
                b2w[nxt][0] = PW2[(size_t)((w * 2 + 0) * 8 + ks3 + 1) * 64 + l];
                b2w[nxt][1] = PW2[(size_t)((w * 2 + 1) * 8 + ks3 + 1) * 64 + l];
            } else {
                b2w[nxt][0] = PW2[(size_t)((32 + w * 2 + 0) * 8) * 64 + l];
                b2w[nxt][1] = PW2[(size_t)((32 + w * 2 + 1) * 8) * 64 + l];
            }
            short8 af0 = *(const short8*)(LB + 16384 + ((0 * 8 + ks3) << 10) + loff);
            short8 af1 = *(const short8*)(LB + 16384 + ((1 * 8 + ks3) << 10) + loff);
            __builtin_amdgcn_s_setprio(1);
            acc[0][0] = __builtin_amdgcn_mfma_f32_16x16x32_bf16(af0, b2w[cur][0], acc[0][0], 0, 0, 0);
            acc[0][1] = __builtin_amdgcn_mfma_f32_16x16x32_bf16(af0, b2w[cur][1], acc[0][1], 0, 0, 0);
            acc[1][0] = __builtin_amdgcn_mfma_f32_16x16x32_bf16(af1, b2w[cur][0], acc[1][0], 0, 0, 0);
            acc[1][1] = __builtin_amdgcn_mfma_f32_16x16x32_bf16(af1, b2w[cur][1], acc[1][1], 0, 0, 0);
            __builtin_amdgcn_s_setprio(0);
        }
        // sdelta = (ss+bss) + sv*dot -> slotX [a][c] (norm frags dead since B4)
#pragma unroll
        for (int cf = 0; cf < 2; cf++) {
            int c = (w << 5) + (cf << 4) + l15;
            float bss = b2[c];
#pragma unroll
            for (int g = 0; g < 2; g++)
#pragma unroll
                for (int j = 0; j < 4; j++) {
                    int a = (g << 4) + (lhi << 2) + j;
                    float sd = (acc[g][cf][j] + bss) + svd[cf][g][j];
                    int bo = ((a << 9) + (c << 1)) ^ ((a & 7) << 4);
                    *(unsigned short*)(LB + bo) = f2bf(sd);
                }
        }
    }
    {   // vv (sg=2) -> a_vv kept in regs (svd reused)
        floatx4 acc[2][2];
#pragma unroll
        for (int g = 0; g < 2; g++) { acc[g][0] = (floatx4)0.f; acc[g][1] = (floatx4)0.f; }
#pragma unroll
        for (int ks3 = 0; ks3 < 8; ks3++) {
            int cur = ks3 & 1, nxt = cur ^ 1;
            if (ks3 < 7) {
                b2w[nxt][0] = PW2[(size_t)((32 + w * 2 + 0) * 8 + ks3 + 1) * 64 + l];
                b2w[nxt][1] = PW2[(size_t)((32 + w * 2 + 1) * 8 + ks3 + 1) * 64 + l];
            }
            short8 af0 = *(const short8*)(LB + 16384 + ((0 * 8 + ks3) << 10) + loff);
            short8 af1 = *(const short8*)(LB + 16384 + ((1 * 8 + ks3) << 10) + loff);
            __builtin_amdgcn_s_setprio(1);
            acc[0][0] = __builtin_amdgcn_mfma_f32_16x16x32_bf16(af0, b2w[cur][0], acc[0][0], 0, 0, 0);
            acc[0][1] = __builtin_amdgcn_mfma_f32_16x16x32_bf16(af0, b2w[cur][1], acc[0][1], 0, 0, 0);
            acc[1][0] = __builtin_amdgcn_mfma_f32_16x16x32_bf16(af1, b2w[cur][0], acc[1][0], 0, 0, 0);
            acc[1][1] = __builtin_amdgcn_mfma_f32_16x16x32_bf16(af1, b2w[cur][1], acc[1][1], 0, 0, 0);
            __builtin_amdgcn_s_setprio(0);
        }
#pragma unroll
        for (int cf = 0; cf < 2; cf++) {
            float bvv = b2[512 + (w << 5) + (cf << 4) + l15];
#pragma unroll
            for (int g = 0; g < 2; g++)
#pragma unroll
                for (int j = 0; j < 4; j++)
                    svd[cf][g][j] = acc[g][cf][j] + bvv;
        }
    }

    BAR();  // B5: sdelta visible

    // ---- epilogue: s_out (LN map; raw s from regs; nt store) ----
    {
        size_t gb = (size_t)(atom0 + aLN) * H;
        int xo = (aLN & 7) << 4;
#pragma unroll
        for (int i = 0; i < 4; i++) {
            int chunk = lg + (i << 4);
            short4v sd4 = *(const short4v*)(LB + (((aLN << 9) + (chunk << 3)) ^ xo));
            floatx4 o;
#pragma unroll
            for (int j = 0; j < 4; j++) o[j] = bf2f((unsigned short)srp[i][j]) + bf2f((unsigned short)sd4[j]);
            __builtin_nontemporal_store(o, (floatx4*)(s_out + gb + chunk * 4));
        }
    }

    // ---- epilogue: v_out = v(regs) + a_vv * Uv(regs); nt scalar stores ----
#pragma unroll
    for (int cf = 0; cf < 2; cf++) {
        int c = (w << 5) + (cf << 4) + l15;
#pragma unroll
        for (int g = 0; g < 2; g++)
#pragma unroll
            for (int j = 0; j < 4; j++) {
                int a = (g << 4) + (lhi << 2) + j;
                size_t base = (size_t)(atom0 + a) * 3 * H + c;
                float av = svd[cf][g][j];
#pragma unroll
                for (int d = 0; d < 3; d++) {
                    float uv = upk(uvh[cf][d][g][j >> 1], j & 1);
                    float vr = upk(vrw[cf][d][g][j >> 1], j & 1);
                    __builtin_nontemporal_store(vr + av * uv, v_out + base + (size_t)d * H);
                }
            }
    }
}

extern "C" void kernel_launch(void* const* d_in, const int* in_sizes, int n_in,
                              void* d_out, int out_size, void* d_ws, size_t ws_size,
                              hipStream_t stream) {
    const float* s     = (const float*)d_in[0];
    const float* v     = (const float*)d_in[1];
    const float* gamma = (const float*)d_in[2];
    const float* beta  = (const float*)d_in[3];
    const float* U_W   = (const float*)d_in[4];
    const float* V_W   = (const float*)d_in[5];
    const float* W1    = (const float*)d_in[6];
    const float* b1    = (const float*)d_in[7];
    const float* W2    = (const float*)d_in[8];
    const float* b2    = (const float*)d_in[9];
    float* s_out = (float*)d_out;
    float* v_out = s_out + (size_t)NATOMS * H;
    unsigned short* P = (unsigned short*)d_ws;   // needs 917504 B

    pack_weights<<<dim3(224), dim3(256), 0, stream>>>(U_W, V_W, W1, W2, P);
    painn_main<<<dim3(NBLK), dim3(512), 0, stream>>>(s, v, gamma, beta, b1, b2, P, s_out, v_out);
}